// Round 12
// baseline (87.507 us; speedup 1.0000x reference)
//
#include <hip/hip_runtime.h>
#include <hip/hip_bf16.h>

// Attention: B=512, T=128, C=512, H=64. out[b,t,h] f32.
// R12: ABLATION ROUND. R11 kernel templated on VARIANT:
//   V1 = staging skeleton (gload_lds + barriers + vmcnt only)
//   V2 = full projection, stop before attention (acc kept live via asm)
//   V3 = attention phases only (garbage LDS input)
//   V0 = full kernel (launched last -> correct d_out)
// All four launched sequentially; rocprof separates them. Wall time is the
// sum -- this is a measurement round.

#define TT 128
#define CC 512
#define HH 64

typedef __attribute__((ext_vector_type(8))) short bf16x8;
typedef __attribute__((ext_vector_type(4))) float f32x4;

__device__ __forceinline__ ushort f2bf(float f) {
    union { float f; unsigned u; } v; v.f = f;
    unsigned r = v.u + 0x7fffu + ((v.u >> 16) & 1u);  // RNE
    return (ushort)(r >> 16);
}

__device__ __forceinline__ void gload_lds16(const void* g, void* l) {
    __builtin_amdgcn_global_load_lds(
        (const __attribute__((address_space(1))) unsigned int*)g,
        (__attribute__((address_space(3))) unsigned int*)l, 16, 0, 0);
}

// ---- wpack: chunk kt stride 8192 ushorts (16KB, last 4KB pad unused) ----
__global__ void wpack_kernel(const float* __restrict__ wq,
                             const float* __restrict__ wk,
                             const float* __restrict__ wv,
                             ushort* __restrict__ wpk) {
    int p = blockIdx.x * 256 + threadIdx.x;   // 0..98303
    int j  = p & 7;
    int l  = (p >> 3) & 63;
    int nt = (p >> 9) % 12;
    int kt = p / (12 * 512);
    int w  = nt >> 2;
    const float* src = (w == 0) ? wq : ((w == 1) ? wk : wv);
    int h = (nt & 3) * 16 + (l & 15);
    int c = kt * 32 + ((l >> 4) << 3) + j;
    wpk[kt * 8192 + ((nt * 64 + l) * 8) + j] = f2bf(src[h * 512 + c]);
}

// ---- fused kernel, templated ablation variant ----
template<int V>
__launch_bounds__(512, 4)
__global__ void attn_fused_kernel(const float* __restrict__ x,
                                  const ushort* __restrict__ wpk,
                                  float* __restrict__ out,
                                  float* __restrict__ scratch) {
    __shared__ __align__(16) char smem[65536];
    ushort* qs  = (ushort*)smem;               // [128][64] swizzled col^((t&7)<<3)
    ushort* ks  = (ushort*)(smem + 16384);     // [128][64] swizzled
    ushort* vst = (ushort*)(smem + 32768);     // [64][128] V^T, swizzled t^((h&7)<<3)
    ushort* ps  = (ushort*)smem;               // [128][128] P overlay, swizzled

    const int tid  = threadIdx.x;
    const int wave = tid >> 6;
    const int lane = tid & 63;
    const int lq   = lane >> 4;
    const int lr   = lane & 15;
    const int b    = blockIdx.x;
    const size_t bB = (size_t)b * TT;

    const f32x4 fzero = {0.f, 0.f, 0.f, 0.f};

    f32x4 acc[12];
    #pragma unroll
    for (int j = 0; j < 12; ++j) acc[j] = fzero;

    auto stage = [&](int kt, int s) {
        const char* wsrc = (const char*)(wpk + kt * 8192);
        char* wdst = smem + s * 16384;
        #pragma unroll
        for (int p = 0; p < 2; ++p) {
            int off = wave * 2048 + p * 1024;
            gload_lds16(wsrc + off + lane * 16, wdst + off);
        }
        char* xdst = smem + 32768 + s * 16384;
        #pragma unroll
        for (int p = 0; p < 2; ++p) {
            int uoff = wave * 2048 + p * 1024;
            int off  = uoff + lane * 16;
            int row  = off >> 7;
            int slot = (off >> 4) & 7;
            int g    = slot ^ (row & 7);
            const float* src = x + (bB + row) * CC + kt * 32 + g * 4;
            gload_lds16(src, xdst + uoff);
        }
    };

    const int r = wave * 16 + lr;

    if constexpr (V != 3) {
        // ================= Phase 1: QKV projection =================
        stage(0, 0);
        for (int kt = 0; kt < 16; ++kt) {
            const int cur = kt & 1;
            __builtin_amdgcn_s_barrier();
            if (kt + 1 < 16) {
                stage(kt + 1, cur ^ 1);
                asm volatile("s_waitcnt vmcnt(4)" ::: "memory");
            } else {
                asm volatile("s_waitcnt vmcnt(0)" ::: "memory");
            }
            __builtin_amdgcn_sched_barrier(0);
            __builtin_amdgcn_s_barrier();
            __builtin_amdgcn_sched_barrier(0);

            if constexpr (V != 1) {
                const float* xs = (const float*)(smem + 32768 + cur * 16384);
                int s0 = (lq * 2) ^ (r & 7);
                int s1 = (lq * 2 + 1) ^ (r & 7);
                f32x4 alo = *(const f32x4*)(xs + r * 32 + s0 * 4);
                f32x4 ahi = *(const f32x4*)(xs + r * 32 + s1 * 4);

                const ushort* wf = (const ushort*)(smem + cur * 16384);
                bf16x8 w[12];
                #pragma unroll
                for (int nt = 0; nt < 12; ++nt)
                    w[nt] = *(const bf16x8*)(wf + (nt * 64 + lane) * 8);

                bf16x8 a;
                a[0] = (short)f2bf(alo[0]); a[1] = (short)f2bf(alo[1]);
                a[2] = (short)f2bf(alo[2]); a[3] = (short)f2bf(alo[3]);
                a[4] = (short)f2bf(ahi[0]); a[5] = (short)f2bf(ahi[1]);
                a[6] = (short)f2bf(ahi[2]); a[7] = (short)f2bf(ahi[3]);

                #pragma unroll
                for (int nt = 0; nt < 12; ++nt)
                    acc[nt] = __builtin_amdgcn_mfma_f32_16x16x32_bf16(a, w[nt], acc[nt], 0, 0, 0);
            }
        }
    }

    if constexpr (V == 1) {
        // staging skeleton only; tiny store so the kernel has a global effect
        if (tid == 0) scratch[b] = 1.0f;
        return;
    }

    if constexpr (V == 2) {
        // keep acc live (rule #17: prevent DCE without cost), then stop
        #pragma unroll
        for (int nt = 0; nt < 12; ++nt) {
            float v = acc[nt][0] + acc[nt][1] + acc[nt][2] + acc[nt][3];
            asm volatile("" :: "v"(v));
        }
        if (tid == 0) scratch[b] = acc[0][0];
        return;
    }

    if constexpr (V == 0) {
        __syncthreads();
        // ---- QKV -> attention LDS ----
        #pragma unroll
        for (int nt = 0; nt < 12; ++nt)
            #pragma unroll
            for (int j = 0; j < 4; ++j) {
                int t = wave * 16 + lq * 4 + j;
                int h = (nt & 3) * 16 + lr;
                ushort v = f2bf(acc[nt][j]);
                if (nt < 4)      qs[t * 64 + (h ^ ((t & 7) << 3))] = v;
                else if (nt < 8) ks[t * 64 + (h ^ ((t & 7) << 3))] = v;
                else             vst[h * 128 + (t ^ ((h & 7) << 3))] = v;
            }
    }
    __syncthreads();

    // ================= Phase 2: S = Q K^T, causal softmax =================
    const int row0 = wave * 16;
    f32x4 s[8];
    #pragma unroll
    for (int j = 0; j < 8; ++j) s[j] = fzero;

    #pragma unroll
    for (int kt = 0; kt < 2; ++kt) {
        int h0 = kt * 32 + lq * 8;
        int t  = row0 + lr;
        bf16x8 a = *(const bf16x8*)&qs[t * 64 + (h0 ^ ((t & 7) << 3))];
        bf16x8 kf[8];
        #pragma unroll
        for (int nt = 0; nt < 8; ++nt) {
            int sc = nt * 16 + lr;
            kf[nt] = *(const bf16x8*)&ks[sc * 64 + (h0 ^ ((sc & 7) << 3))];
        }
        #pragma unroll
        for (int nt = 0; nt < 8; ++nt)
            s[nt] = __builtin_amdgcn_mfma_f32_16x16x32_bf16(a, kf[nt], s[nt], 0, 0, 0);
    }

    float rinv[4];
    #pragma unroll
    for (int j = 0; j < 4; ++j) {
        int t = row0 + lq * 4 + j;
        float m = -1e30f;
        #pragma unroll
        for (int nt = 0; nt < 8; ++nt) {
            int sc = nt * 16 + lr;
            float v = s[nt][j] * 0.125f;
            v = (sc <= t) ? v : -1e30f;
            s[nt][j] = v;
            m = fmaxf(m, v);
        }
        m = fmaxf(m, __shfl_xor(m, 1));
        m = fmaxf(m, __shfl_xor(m, 2));
        m = fmaxf(m, __shfl_xor(m, 4));
        m = fmaxf(m, __shfl_xor(m, 8));
        float sum = 0.f;
        #pragma unroll
        for (int nt = 0; nt < 8; ++nt) {
            float p = __expf(s[nt][j] - m);
            s[nt][j] = p;
            sum += p;
        }
        sum += __shfl_xor(sum, 1);
        sum += __shfl_xor(sum, 2);
        sum += __shfl_xor(sum, 4);
        sum += __shfl_xor(sum, 8);
        rinv[j] = 1.0f / sum;
    }

    __syncthreads();

    #pragma unroll
    for (int j = 0; j < 4; ++j) {
        int t = row0 + lq * 4 + j;
        #pragma unroll
        for (int nt = 0; nt < 8; ++nt) {
            int sc = nt * 16 + lr;
            ps[t * 128 + (sc ^ ((t & 7) << 3))] = f2bf(s[nt][j]);
        }
    }
    __syncthreads();

    // ================= Phase 3: O = P V =================
    f32x4 o[4];
    #pragma unroll
    for (int j = 0; j < 4; ++j) o[j] = fzero;

    #pragma unroll
    for (int ksv = 0; ksv < 4; ++ksv) {
        int s0 = ksv * 32 + lq * 8;
        int t  = row0 + lr;
        bf16x8 a = *(const bf16x8*)&ps[t * 128 + (s0 ^ ((t & 7) << 3))];
        bf16x8 vf[4];
        #pragma unroll
        for (int nt = 0; nt < 4; ++nt) {
            int h = nt * 16 + lr;
            vf[nt] = *(const bf16x8*)&vst[h * 128 + (s0 ^ ((h & 7) << 3))];
        }
        #pragma unroll
        for (int nt = 0; nt < 4; ++nt)
            o[nt] = __builtin_amdgcn_mfma_f32_16x16x32_bf16(a, vf[nt], o[nt], 0, 0, 0);
    }

    float* dst = (V == 0) ? (out + (size_t)b * (TT * HH))
                          : (scratch + 512 + (size_t)b * (TT * HH));
    #pragma unroll
    for (int nt = 0; nt < 4; ++nt)
        #pragma unroll
        for (int j = 0; j < 4; ++j) {
            int t = row0 + lq * 4 + j;
            int h = nt * 16 + lr;
            dst[t * HH + h] = o[nt][j] * rinv[j];
        }
}

extern "C" void kernel_launch(void* const* d_in, const int* in_sizes, int n_in,
                              void* d_out, int out_size, void* d_ws, size_t ws_size,
                              hipStream_t stream) {
    const float* x  = (const float*)d_in[0];
    const float* wq = (const float*)d_in[1];
    const float* wk = (const float*)d_in[2];
    const float* wv = (const float*)d_in[3];
    float* o = (float*)d_out;
    ushort* wpk = (ushort*)d_ws;                        // 256 KB packed W
    float* scratch = (float*)((char*)d_ws + 262144);    // ablation sink

    (void)in_sizes; (void)n_in; (void)out_size; (void)ws_size;

    wpack_kernel<<<384, 256, 0, stream>>>(wq, wk, wv, wpk);
    attn_fused_kernel<1><<<512, 512, 0, stream>>>(x, wpk, o, scratch);
    attn_fused_kernel<2><<<512, 512, 0, stream>>>(x, wpk, o, scratch);
    attn_fused_kernel<3><<<512, 512, 0, stream>>>(x, wpk, o, scratch);
    attn_fused_kernel<0><<<512, 512, 0, stream>>>(x, wpk, o, scratch);
}

// Round 13
// 40.272 us; speedup vs baseline: 2.1729x; 2.1729x over previous
//
#include <hip/hip_runtime.h>
#include <hip/hip_bf16.h>

// Attention: B=512, T=128, C=512, H=64. out[b,t,h] f32.
// R13: x never staged through LDS (per-wave rows only -> inline-asm register
// loads, 2 chunks ahead); BK=64 (8 chunks, 16 barriers instead of 32);
// W staged via global_load_lds into 2x24KB LDS dbuf (dense 12KB sub-chunks).
// Counted vmcnt: wait-x=vmcnt(7), wait-W=vmcnt(11) steady state.
// Attention phases (QK^T -> in-reg causal softmax -> PV) unchanged from R11.

#define TT 128
#define CC 512
#define HH 64

typedef __attribute__((ext_vector_type(8))) short bf16x8;
typedef __attribute__((ext_vector_type(4))) float f32x4;

__device__ __forceinline__ ushort f2bf(float f) {
    union { float f; unsigned u; } v; v.f = f;
    unsigned r = v.u + 0x7fffu + ((v.u >> 16) & 1u);  // RNE
    return (ushort)(r >> 16);
}

__device__ __forceinline__ bf16x8 pack8(f32x4 lo, f32x4 hi) {
    bf16x8 a;
    a[0] = (short)f2bf(lo[0]); a[1] = (short)f2bf(lo[1]);
    a[2] = (short)f2bf(lo[2]); a[3] = (short)f2bf(lo[3]);
    a[4] = (short)f2bf(hi[0]); a[5] = (short)f2bf(hi[1]);
    a[6] = (short)f2bf(hi[2]); a[7] = (short)f2bf(hi[3]);
    return a;
}

__device__ __forceinline__ void gload_lds16(const void* g, void* l) {
    __builtin_amdgcn_global_load_lds(
        (const __attribute__((address_space(1))) unsigned int*)g,
        (__attribute__((address_space(3))) unsigned int*)l, 16, 0, 0);
}

// ---- wpack: dense 12KB sub-chunks ks in [0,16) ----
// idx = ((ks*12 + nt)*64 + lane)*8 + j ; value = W_{nt>>2}[h][c],
// h = (nt&3)*16 + (lane&15), c = ks*32 + (lane>>4)*8 + j
__global__ void wpack_kernel(const float* __restrict__ wq,
                             const float* __restrict__ wk,
                             const float* __restrict__ wv,
                             ushort* __restrict__ wpk) {
    int p = blockIdx.x * 256 + threadIdx.x;   // 0..98303
    int j  = p & 7;
    int l  = (p >> 3) & 63;
    int nt = (p >> 9) % 12;
    int ks = p / (12 * 512);
    int w  = nt >> 2;
    const float* src = (w == 0) ? wq : ((w == 1) ? wk : wv);
    int h = (nt & 3) * 16 + (l & 15);
    int c = ks * 32 + ((l >> 4) << 3) + j;
    wpk[p] = f2bf(src[h * 512 + c]);
}

// ---- fused: one block per batch element; 8 waves; 512 blocks ----
__launch_bounds__(512, 4)
__global__ void attn_fused_kernel(const float* __restrict__ x,
                                  const ushort* __restrict__ wpk,
                                  float* __restrict__ out) {
    // 48 KB LDS union -> 2 blocks/CU.
    // projection: [0,49152) = W dbuf 2x24KB.
    // attention:  [0,16384) qs, [16384,32768) ksm, [32768,49152) vst,
    //             ps = [0,32768) overlay.
    __shared__ __align__(16) char smem[49152];
    ushort* qs  = (ushort*)smem;               // [128][64] swizzled col^((t&7)<<3)
    ushort* ksm = (ushort*)(smem + 16384);     // [128][64] swizzled
    ushort* vst = (ushort*)(smem + 32768);     // [64][128] V^T, swizzled t^((h&7)<<3)
    ushort* ps  = (ushort*)smem;               // [128][128] P overlay, swizzled

    const int tid  = threadIdx.x;
    const int wave = tid >> 6;
    const int lane = tid & 63;
    const int lq   = lane >> 4;
    const int lr   = lane & 15;
    const int b    = blockIdx.x;
    const size_t bB = (size_t)b * TT;

    const f32x4 fzero = {0.f, 0.f, 0.f, 0.f};

    // ================= Phase 1: QKV projection (8 chunks of K=64) =========
    f32x4 acc[12];
    #pragma unroll
    for (int j = 0; j < 12; ++j) acc[j] = fzero;

    const int r = wave * 16 + lr;                  // block-local row
    const float* xr = x + (bB + r) * CC + lq * 8;  // this lane's x base

    // W chunk kt (24KB) -> LDS buf s; 3 x 1KB gload_lds per wave
    auto stageW = [&](int kt, int s) {
        const char* wsrc = (const char*)wpk + kt * 24576;
        char* wdst = smem + s * 24576;
        #pragma unroll
        for (int p = 0; p < 3; ++p) {
            int off = wave * 3072 + p * 1024;
            gload_lds16(wsrc + off + lane * 16, wdst + off);
        }
    };

    // x chunk kt -> 4 dwordx4 into named regs (inline asm so the prefetch
    // cannot be folded; counted in vmcnt)
    #define LOADX(kt, d0, d1, d2, d3)                                          \
        {                                                                      \
            const float* p0 = xr + (kt) * 64;                                  \
            asm volatile("global_load_dwordx4 %0, %1, off"                     \
                         : "=&v"(d0) : "v"(p0) : "memory");                    \
            asm volatile("global_load_dwordx4 %0, %1, off offset:16"           \
                         : "=&v"(d1) : "v"(p0) : "memory");                    \
            asm volatile("global_load_dwordx4 %0, %1, off offset:128"          \
                         : "=&v"(d2) : "v"(p0) : "memory");                    \
            asm volatile("global_load_dwordx4 %0, %1, off offset:144"          \
                         : "=&v"(d3) : "v"(p0) : "memory");                    \
        }

    f32x4 xA0, xA1, xA2, xA3, xB0, xB1, xB2, xB3;

    stageW(0, 0);                 // ops: W0(3)
    LOADX(0, xA0, xA1, xA2, xA3); // x0(4)
    LOADX(1, xB0, xB1, xB2, xB3); // x1(4)

    #pragma unroll
    for (int kt = 0; kt < 8; ++kt) {
        const int cur = kt & 1;

        // all waves done with compute(kt-1) -> W buf cur^1 reusable
        __builtin_amdgcn_s_barrier();

        // wait for x(kt): newer ops = W(kt)3 + x(kt+1)4 (steady)
        if (kt == 0)      asm volatile("s_waitcnt vmcnt(4)" ::: "memory");
        else if (kt == 7) asm volatile("s_waitcnt vmcnt(3)" ::: "memory");
        else              asm volatile("s_waitcnt vmcnt(7)" ::: "memory");
        __builtin_amdgcn_sched_barrier(0);

        // consume x(kt) -> A fragments (before reissuing into the slot)
        bf16x8 a0, a1;
        if (cur == 0) { a0 = pack8(xA0, xA1); a1 = pack8(xA2, xA3); }
        else          { a0 = pack8(xB0, xB1); a1 = pack8(xB2, xB3); }

        // issue next stages
        if (kt + 1 < 8) stageW(kt + 1, cur ^ 1);
        if (kt + 2 < 8) {
            if (cur == 0) LOADX(kt + 2, xA0, xA1, xA2, xA3)
            else          LOADX(kt + 2, xB0, xB1, xB2, xB3)
        }

        // wait for W(kt): newer ops = x(kt+1)4 + W(kt+1)3 + x(kt+2)4 (steady)
        if (kt <= 5)      asm volatile("s_waitcnt vmcnt(11)" ::: "memory");
        else if (kt == 6) asm volatile("s_waitcnt vmcnt(7)" ::: "memory");
        else              asm volatile("s_waitcnt vmcnt(0)" ::: "memory");
        __builtin_amdgcn_sched_barrier(0);
        __builtin_amdgcn_s_barrier();      // W(kt) visible from all waves
        __builtin_amdgcn_sched_barrier(0);

        const ushort* wf = (const ushort*)(smem + cur * 24576);
        #pragma unroll
        for (int kh = 0; kh < 2; ++kh) {
            bf16x8 a = kh ? a1 : a0;
            #pragma unroll
            for (int nt = 0; nt < 12; ++nt) {
                bf16x8 bb = *(const bf16x8*)(wf + kh * 6144 + (nt * 64 + lane) * 8);
                acc[nt] = __builtin_amdgcn_mfma_f32_16x16x32_bf16(a, bb, acc[nt], 0, 0, 0);
            }
        }
    }

    __syncthreads();   // compute(7) done everywhere before overlay writes

    // ---- QKV -> attention LDS (overlays W dbuf) ----
    #pragma unroll
    for (int nt = 0; nt < 12; ++nt)
        #pragma unroll
        for (int j = 0; j < 4; ++j) {
            int t = wave * 16 + lq * 4 + j;
            int h = (nt & 3) * 16 + lr;
            ushort v = f2bf(acc[nt][j]);
            if (nt < 4)      qs[t * 64 + (h ^ ((t & 7) << 3))] = v;
            else if (nt < 8) ksm[t * 64 + (h ^ ((t & 7) << 3))] = v;
            else             vst[h * 128 + (t ^ ((h & 7) << 3))] = v;
        }
    __syncthreads();

    // ================= Phase 2: S = Q K^T, causal softmax =================
    const int row0 = wave * 16;
    f32x4 s[8];
    #pragma unroll
    for (int j = 0; j < 8; ++j) s[j] = fzero;

    #pragma unroll
    for (int kt = 0; kt < 2; ++kt) {
        int h0 = kt * 32 + lq * 8;
        int t  = row0 + lr;
        bf16x8 a = *(const bf16x8*)&qs[t * 64 + (h0 ^ ((t & 7) << 3))];
        bf16x8 kf[8];
        #pragma unroll
        for (int nt = 0; nt < 8; ++nt) {
            int sc = nt * 16 + lr;
            kf[nt] = *(const bf16x8*)&ksm[sc * 64 + (h0 ^ ((sc & 7) << 3))];
        }
        #pragma unroll
        for (int nt = 0; nt < 8; ++nt)
            s[nt] = __builtin_amdgcn_mfma_f32_16x16x32_bf16(a, kf[nt], s[nt], 0, 0, 0);
    }

    float rinv[4];
    #pragma unroll
    for (int j = 0; j < 4; ++j) {
        int t = row0 + lq * 4 + j;
        float m = -1e30f;
        #pragma unroll
        for (int nt = 0; nt < 8; ++nt) {
            int sc = nt * 16 + lr;
            float v = s[nt][j] * 0.125f;
            v = (sc <= t) ? v : -1e30f;        // causal mask
            s[nt][j] = v;
            m = fmaxf(m, v);
        }
        m = fmaxf(m, __shfl_xor(m, 1));
        m = fmaxf(m, __shfl_xor(m, 2));
        m = fmaxf(m, __shfl_xor(m, 4));
        m = fmaxf(m, __shfl_xor(m, 8));
        float sum = 0.f;
        #pragma unroll
        for (int nt = 0; nt < 8; ++nt) {
            float p = __expf(s[nt][j] - m);
            s[nt][j] = p;
            sum += p;
        }
        sum += __shfl_xor(sum, 1);
        sum += __shfl_xor(sum, 2);
        sum += __shfl_xor(sum, 4);
        sum += __shfl_xor(sum, 8);
        rinv[j] = 1.0f / sum;                  // deferred normalization
    }

    __syncthreads();   // all qs/ksm reads done before P overlay writes

    #pragma unroll
    for (int j = 0; j < 4; ++j) {
        int t = row0 + lq * 4 + j;
        #pragma unroll
        for (int nt = 0; nt < 8; ++nt) {
            int sc = nt * 16 + lr;
            ps[t * 128 + (sc ^ ((t & 7) << 3))] = f2bf(s[nt][j]);
        }
    }
    __syncthreads();

    // ================= Phase 3: O = P V =================
    f32x4 o[4];
    #pragma unroll
    for (int j = 0; j < 4; ++j) o[j] = fzero;

    #pragma unroll
    for (int ksv = 0; ksv < 4; ++ksv) {
        int s0 = ksv * 32 + lq * 8;
        int t  = row0 + lr;
        bf16x8 a = *(const bf16x8*)&ps[t * 128 + (s0 ^ ((t & 7) << 3))];
        bf16x8 vf[4];
        #pragma unroll
        for (int nt = 0; nt < 4; ++nt) {
            int h = nt * 16 + lr;
            vf[nt] = *(const bf16x8*)&vst[h * 128 + (s0 ^ ((h & 7) << 3))];
        }
        #pragma unroll
        for (int nt = 0; nt < 4; ++nt)
            o[nt] = __builtin_amdgcn_mfma_f32_16x16x32_bf16(a, vf[nt], o[nt], 0, 0, 0);
    }

    float* ob = out + (size_t)b * (TT * HH);
    #pragma unroll
    for (int nt = 0; nt < 4; ++nt)
        #pragma unroll
        for (int j = 0; j < 4; ++j) {
            int t = row0 + lq * 4 + j;
            int h = nt * 16 + lr;
            ob[t * HH + h] = o[nt][j] * rinv[j];
        }
}

extern "C" void kernel_launch(void* const* d_in, const int* in_sizes, int n_in,
                              void* d_out, int out_size, void* d_ws, size_t ws_size,
                              hipStream_t stream) {
    const float* x  = (const float*)d_in[0];
    const float* wq = (const float*)d_in[1];
    const float* wk = (const float*)d_in[2];
    const float* wv = (const float*)d_in[3];
    float* o = (float*)d_out;
    ushort* wpk = (ushort*)d_ws;    // 192 KB dense packed W fragments

    (void)in_sizes; (void)n_in; (void)out_size; (void)ws_size;

    wpack_kernel<<<384, 256, 0, stream>>>(wq, wk, wv, wpk);
    attn_fused_kernel<<<512, 512, 0, stream>>>(x, wpk, o);
}